// Round 3
// baseline (1563.319 us; speedup 1.0000x reference)
//
#include <hip/hip_runtime.h>
#include <hip/hip_bf16.h>

// GCN forward, CSR-gather + fused gather/GEMM formulation:
//   layer L: block gathers 64 node rows (Anorm @ h, via dst-sorted CSR) into LDS,
//   then register-tiled GEMM vs W staged in LDS chunks. Layer 2 fuses bias+ReLU+
//   pre-reduced segment-max pooling (batch is sorted -> flush-on-change atomics).

#define NN 100000
#define NE 1600000
#define NG 512
#define NBLK ((NN + 1023) / 1024)   // 98 scan blocks

// ---------------- CSR build (counting sort by dst) ----------------

__global__ void k_zero_int(int* p, int n) {
    int i = blockIdx.x * blockDim.x + threadIdx.x;
    if (i < n) p[i] = 0;
}

__global__ void k_fill(float* p, float v, int n) {
    int i = blockIdx.x * blockDim.x + threadIdx.x;
    if (i < n) p[i] = v;
}

__global__ void k_hist(const int* __restrict__ dst, int* cnt, int e) {
    int i = blockIdx.x * blockDim.x + threadIdx.x;
    if (i < e) atomicAdd(&cnt[dst[i]], 1);
}

__global__ void k_dinv(const int* __restrict__ cnt, float* __restrict__ dinv, int n) {
    int i = blockIdx.x * blockDim.x + threadIdx.x;
    if (i < n) dinv[i] = rsqrtf((float)cnt[i] + 1.0f);
}

__global__ __launch_bounds__(256) void k_bsum(const int* __restrict__ cnt, int* __restrict__ bsum) {
    __shared__ int s[256];
    int b = blockIdx.x, t = threadIdx.x;
    int base = b * 1024 + t * 4;
    int v = 0;
#pragma unroll
    for (int j = 0; j < 4; j++) { int i = base + j; if (i < NN) v += cnt[i]; }
    s[t] = v; __syncthreads();
    for (int off = 128; off > 0; off >>= 1) {
        if (t < off) s[t] += s[t + off];
        __syncthreads();
    }
    if (t == 0) bsum[b] = s[0];
}

__global__ __launch_bounds__(128) void k_scan_bsum(int* bsum, int* row_ptr) {
    __shared__ int s[128];
    int t = threadIdx.x;
    int v = (t < NBLK) ? bsum[t] : 0;
    s[t] = v; __syncthreads();
    for (int off = 1; off < 128; off <<= 1) {
        int u = (t >= off) ? s[t - off] : 0;
        __syncthreads();
        s[t] += u;
        __syncthreads();
    }
    if (t < NBLK) bsum[t] = s[t] - v;
    if (t == 0) row_ptr[NN] = NE;
}

__global__ __launch_bounds__(256) void k_scan_blocks(const int* __restrict__ cnt,
    const int* __restrict__ bsum, int* __restrict__ row_ptr, int* __restrict__ cursor) {
    __shared__ int s[256];
    int b = blockIdx.x, t = threadIdx.x;
    int base = b * 1024 + t * 4;
    int v[4]; int sum = 0;
#pragma unroll
    for (int j = 0; j < 4; j++) { int i = base + j; v[j] = (i < NN) ? cnt[i] : 0; sum += v[j]; }
    s[t] = sum; __syncthreads();
    for (int off = 1; off < 256; off <<= 1) {
        int u = (t >= off) ? s[t - off] : 0;
        __syncthreads();
        s[t] += u;
        __syncthreads();
    }
    int excl = s[t] - sum + bsum[b];
#pragma unroll
    for (int j = 0; j < 4; j++) {
        int i = base + j;
        if (i < NN) { row_ptr[i] = excl; cursor[i] = excl; excl += v[j]; }
    }
}

__global__ void k_fillslots(const int* __restrict__ src, const int* __restrict__ dst,
    const float* __restrict__ dinv, int* cursor,
    int* __restrict__ src_s, float* __restrict__ w_s, int e) {
    int i = blockIdx.x * blockDim.x + threadIdx.x;
    if (i >= e) return;
    int s = src[i], d = dst[i];
    int pos = atomicAdd(&cursor[d], 1);
    src_s[pos] = s;
    w_s[pos] = dinv[s] * dinv[d];
}

// ---------------- layer 1: fused gather(x,78) + GEMM W1[78,128] -> h1 ----------------
// block: 64 nodes. gather: 4 waves x 16 nodes, feat per lane. compute: 32tx x 8ty,
// thread tile = 8 nodes x 4 feats. K padded 78->80 (zeros both sides).
__global__ __launch_bounds__(256, 3) void k_l1_fused(
    const float* __restrict__ x, const int* __restrict__ rp,
    const int* __restrict__ src_s, const float* __restrict__ w_s,
    const float* __restrict__ dinv, const float* __restrict__ W1,
    const float* __restrict__ b1, float* __restrict__ h1) {
    __shared__ float As[64][80];    // 20.5 KB
    __shared__ float Ws[40][128];   // 20.5 KB chunk
    int tid = threadIdx.x;
    int n0 = blockIdx.x * 64;
    int wv = tid >> 6, l = tid & 63;

    // ---- gather phase ----
    for (int ii = 0; ii < 16; ii++) {
        int nl = wv * 16 + ii;
        int n = n0 + nl;
        if (n >= NN) break;
        float di = dinv[n], sw = di * di;
        const float* hn = x + (size_t)n * 78;
        float a0 = hn[l] * sw;
        float a1 = (l < 14) ? hn[64 + l] * sw : 0.0f;
        int e = rp[n], e1 = rp[n + 1];
        for (; e + 1 < e1; e += 2) {
            int s0 = src_s[e], s1 = src_s[e + 1];
            float w0 = w_s[e], w1 = w_s[e + 1];
            const float* p0 = x + (size_t)s0 * 78;
            const float* p1 = x + (size_t)s1 * 78;
            a0 += p0[l] * w0 + p1[l] * w1;
            if (l < 14) a1 += p0[64 + l] * w0 + p1[64 + l] * w1;
        }
        if (e < e1) {
            int s0 = src_s[e]; float w0 = w_s[e];
            const float* p0 = x + (size_t)s0 * 78;
            a0 += p0[l] * w0;
            if (l < 14) a1 += p0[64 + l] * w0;
        }
        As[nl][l] = a0;
        if (l < 16) As[nl][64 + l] = (l < 14) ? a1 : 0.0f;  // zero pad k=78,79
    }

    // ---- compute phase ----
    int tx = tid & 31, ty = tid >> 5;   // tx: 4 feats, ty: 8 nodes
    int f0 = tx * 4;
    float4 acc[8];
#pragma unroll
    for (int i = 0; i < 8; i++) acc[i] = make_float4(0.f, 0.f, 0.f, 0.f);

    for (int c = 0; c < 2; c++) {
        int k0 = c * 40;
        __syncthreads();   // c=0: gather done; c>0: prev chunk consumed
        for (int i = tid; i < 40 * 128; i += 256) {
            int k = k0 + (i >> 7), f = i & 127;
            Ws[i >> 7][f] = (k < 78) ? W1[k * 128 + f] : 0.0f;
        }
        __syncthreads();
#pragma unroll
        for (int kk = 0; kk < 40; kk += 4) {
            float4 w0 = *(const float4*)&Ws[kk + 0][f0];
            float4 w1 = *(const float4*)&Ws[kk + 1][f0];
            float4 w2 = *(const float4*)&Ws[kk + 2][f0];
            float4 w3 = *(const float4*)&Ws[kk + 3][f0];
#pragma unroll
            for (int i = 0; i < 8; i++) {
                float4 a = *(const float4*)&As[ty * 8 + i][k0 + kk];
                acc[i].x += a.x * w0.x + a.y * w1.x + a.z * w2.x + a.w * w3.x;
                acc[i].y += a.x * w0.y + a.y * w1.y + a.z * w2.y + a.w * w3.y;
                acc[i].z += a.x * w0.z + a.y * w1.z + a.z * w2.z + a.w * w3.z;
                acc[i].w += a.x * w0.w + a.y * w1.w + a.z * w2.w + a.w * w3.w;
            }
        }
    }

    float4 bv = *(const float4*)&b1[f0];
#pragma unroll
    for (int i = 0; i < 8; i++) {
        int n = n0 + ty * 8 + i;
        if (n < NN) {
            float4 o;
            o.x = fmaxf(acc[i].x + bv.x, 0.f);
            o.y = fmaxf(acc[i].y + bv.y, 0.f);
            o.z = fmaxf(acc[i].z + bv.z, 0.f);
            o.w = fmaxf(acc[i].w + bv.w, 0.f);
            *(float4*)&h1[(size_t)n * 128 + f0] = o;
        }
    }
}

// ---------------- layer 2: fused gather(h1,128) + GEMM W2[128,256] + max-pool ----------------
// block: 64 nodes. compute: 32tx x 8ty, thread tile = 8 nodes x 8 feats (two halves
// f0=tx*4 and f0+128 so W reads stay stride-1). Pool: flush-on-change (batch sorted).
__global__ __launch_bounds__(256, 3) void k_l2_fused(
    const float* __restrict__ h1, const int* __restrict__ rp,
    const int* __restrict__ src_s, const float* __restrict__ w_s,
    const float* __restrict__ dinv, const float* __restrict__ W2,
    const float* __restrict__ b2, const int* __restrict__ batch,
    unsigned* __restrict__ gmax) {
    __shared__ float As[64][128];   // 32 KB
    __shared__ float Ws[16][256];   // 16 KB chunk
    int tid = threadIdx.x;
    int n0 = blockIdx.x * 64;
    int wv = tid >> 6, l = tid & 63;

    // ---- gather phase (float2 per lane) ----
    for (int ii = 0; ii < 16; ii++) {
        int nl = wv * 16 + ii;
        int n = n0 + nl;
        if (n >= NN) break;
        float di = dinv[n], sw = di * di;
        float2 h0 = ((const float2*)(h1 + (size_t)n * 128))[l];
        float ax = h0.x * sw, ay = h0.y * sw;
        int e = rp[n], e1 = rp[n + 1];
        for (; e + 1 < e1; e += 2) {
            int s0 = src_s[e], s1 = src_s[e + 1];
            float w0 = w_s[e], w1 = w_s[e + 1];
            float2 v0 = ((const float2*)(h1 + (size_t)s0 * 128))[l];
            float2 v1 = ((const float2*)(h1 + (size_t)s1 * 128))[l];
            ax += v0.x * w0 + v1.x * w1;
            ay += v0.y * w0 + v1.y * w1;
        }
        if (e < e1) {
            int s0 = src_s[e]; float w0 = w_s[e];
            float2 v0 = ((const float2*)(h1 + (size_t)s0 * 128))[l];
            ax += v0.x * w0; ay += v0.y * w0;
        }
        float2 o; o.x = ax; o.y = ay;
        ((float2*)As[nl])[l] = o;
    }

    // ---- compute phase ----
    int tx = tid & 31, ty = tid >> 5;
    int f0 = tx * 4;
    float4 aclo[8], achi[8];
#pragma unroll
    for (int i = 0; i < 8; i++) {
        aclo[i] = make_float4(0.f, 0.f, 0.f, 0.f);
        achi[i] = make_float4(0.f, 0.f, 0.f, 0.f);
    }

    for (int c = 0; c < 8; c++) {
        int k0 = c * 16;
        __syncthreads();
        for (int i = tid; i < 1024; i += 256) {   // 16x256 floats as float4
            int k = i >> 6, f4 = (i & 63) * 4;
            *(float4*)&Ws[k][f4] = *(const float4*)&W2[(size_t)(k0 + k) * 256 + f4];
        }
        __syncthreads();
#pragma unroll
        for (int kk = 0; kk < 16; kk += 4) {
            float4 a[8];
#pragma unroll
            for (int i = 0; i < 8; i++) a[i] = *(const float4*)&As[ty * 8 + i][k0 + kk];
#pragma unroll
            for (int j = 0; j < 4; j++) {
                float4 wl = *(const float4*)&Ws[kk + j][f0];
                float4 wh = *(const float4*)&Ws[kk + j][f0 + 128];
#pragma unroll
                for (int i = 0; i < 8; i++) {
                    float s = (j == 0) ? a[i].x : (j == 1) ? a[i].y : (j == 2) ? a[i].z : a[i].w;
                    aclo[i].x += s * wl.x; aclo[i].y += s * wl.y;
                    aclo[i].z += s * wl.z; aclo[i].w += s * wl.w;
                    achi[i].x += s * wh.x; achi[i].y += s * wh.y;
                    achi[i].z += s * wh.z; achi[i].w += s * wh.w;
                }
            }
        }
    }

    // ---- epilogue: bias + relu + pre-reduced segment-max ----
    float4 blo = *(const float4*)&b2[f0];
    float4 bhi = *(const float4*)&b2[f0 + 128];
    int curg = -1;
    float4 mlo = make_float4(0.f, 0.f, 0.f, 0.f), mhi = mlo;
#pragma unroll
    for (int i = 0; i < 8; i++) {
        int n = n0 + ty * 8 + i;
        if (n >= NN) break;
        int g = batch[n];
        float4 vlo, vhi;
        vlo.x = fmaxf(aclo[i].x + blo.x, 0.f); vlo.y = fmaxf(aclo[i].y + blo.y, 0.f);
        vlo.z = fmaxf(aclo[i].z + blo.z, 0.f); vlo.w = fmaxf(aclo[i].w + blo.w, 0.f);
        vhi.x = fmaxf(achi[i].x + bhi.x, 0.f); vhi.y = fmaxf(achi[i].y + bhi.y, 0.f);
        vhi.z = fmaxf(achi[i].z + bhi.z, 0.f); vhi.w = fmaxf(achi[i].w + bhi.w, 0.f);
        if (g != curg) {
            if (curg >= 0) {
                unsigned* gp = &gmax[(size_t)curg * 256];
                atomicMax(&gp[f0 + 0], __float_as_uint(mlo.x));
                atomicMax(&gp[f0 + 1], __float_as_uint(mlo.y));
                atomicMax(&gp[f0 + 2], __float_as_uint(mlo.z));
                atomicMax(&gp[f0 + 3], __float_as_uint(mlo.w));
                atomicMax(&gp[f0 + 128], __float_as_uint(mhi.x));
                atomicMax(&gp[f0 + 129], __float_as_uint(mhi.y));
                atomicMax(&gp[f0 + 130], __float_as_uint(mhi.z));
                atomicMax(&gp[f0 + 131], __float_as_uint(mhi.w));
            }
            curg = g; mlo = vlo; mhi = vhi;
        } else {
            mlo.x = fmaxf(mlo.x, vlo.x); mlo.y = fmaxf(mlo.y, vlo.y);
            mlo.z = fmaxf(mlo.z, vlo.z); mlo.w = fmaxf(mlo.w, vlo.w);
            mhi.x = fmaxf(mhi.x, vhi.x); mhi.y = fmaxf(mhi.y, vhi.y);
            mhi.z = fmaxf(mhi.z, vhi.z); mhi.w = fmaxf(mhi.w, vhi.w);
        }
    }
    if (curg >= 0) {
        unsigned* gp = &gmax[(size_t)curg * 256];
        atomicMax(&gp[f0 + 0], __float_as_uint(mlo.x));
        atomicMax(&gp[f0 + 1], __float_as_uint(mlo.y));
        atomicMax(&gp[f0 + 2], __float_as_uint(mlo.z));
        atomicMax(&gp[f0 + 3], __float_as_uint(mlo.w));
        atomicMax(&gp[f0 + 128], __float_as_uint(mhi.x));
        atomicMax(&gp[f0 + 129], __float_as_uint(mhi.y));
        atomicMax(&gp[f0 + 130], __float_as_uint(mhi.z));
        atomicMax(&gp[f0 + 131], __float_as_uint(mhi.w));
    }
}

// ---------------- MLP head ----------------

__global__ __launch_bounds__(256) void k_gemm3(const float* __restrict__ A,
    const float* __restrict__ W, const float* __restrict__ bias,
    float* __restrict__ out) {
    __shared__ float rs[256];
    int g = blockIdx.x, tid = threadIdx.x;
    rs[tid] = A[g * 256 + tid];
    __syncthreads();
    float acc[4] = {0.f, 0.f, 0.f, 0.f};
    for (int k = 0; k < 256; k++) {
        float a = rs[k];
#pragma unroll
        for (int j = 0; j < 4; j++) acc[j] += a * W[k * 1024 + tid + j * 256];
    }
#pragma unroll
    for (int j = 0; j < 4; j++) {
        int f = tid + j * 256;
        out[g * 1024 + f] = fmaxf(acc[j] + bias[f], 0.0f);
    }
}

__global__ __launch_bounds__(128) void k_gemm4(const float* __restrict__ A,
    const float* __restrict__ W, const float* __restrict__ bias,
    float* __restrict__ out) {
    __shared__ float rs[1024];
    int g = blockIdx.x, tid = threadIdx.x;
    for (int i = tid; i < 1024; i += 128) rs[i] = A[g * 1024 + i];
    __syncthreads();
    float acc = 0.0f;
    for (int k = 0; k < 1024; k++) acc += rs[k] * W[k * 128 + tid];
    out[g * 128 + tid] = acc + bias[tid];
}

extern "C" void kernel_launch(void* const* d_in, const int* in_sizes, int n_in,
                              void* d_out, int out_size, void* d_ws, size_t ws_size,
                              hipStream_t stream) {
    const float* x    = (const float*)d_in[0];
    const int*   ei   = (const int*)d_in[1];
    const int*   batch= (const int*)d_in[2];
    const float* W1   = (const float*)d_in[3];
    const float* b1   = (const float*)d_in[4];
    const float* W2   = (const float*)d_in[5];
    const float* b2   = (const float*)d_in[6];
    const float* Wg1  = (const float*)d_in[7];
    const float* bg1  = (const float*)d_in[8];
    const float* Wg2  = (const float*)d_in[9];
    const float* bg2  = (const float*)d_in[10];
    const int* src = ei;
    const int* dst = ei + NE;

    char* w8 = (char*)d_ws;
    int*   cnt     = (int*)w8;                 w8 += (size_t)NN * 4;
    int*   row_ptr = (int*)w8;                 w8 += (size_t)(NN + 4) * 4;
    int*   cursor  = (int*)w8;                 w8 += (size_t)NN * 4;
    int*   bsum    = (int*)w8;                 w8 += 128 * 4;
    int*   src_s   = (int*)w8;                 w8 += (size_t)NE * 4;
    float* w_s     = (float*)w8;               w8 += (size_t)NE * 4;
    float* dinv    = (float*)w8;               w8 += (size_t)NN * 4;
    float* h1      = (float*)w8;               w8 += (size_t)NN * 128 * 4;
    unsigned* gmax = (unsigned*)w8;            w8 += (size_t)NG * 256 * 4;
    float* g1      = (float*)w8;               w8 += (size_t)NG * 1024 * 4;

    // CSR build
    k_zero_int<<<(NN + 255) / 256, 256, 0, stream>>>(cnt, NN);
    k_hist<<<(NE + 255) / 256, 256, 0, stream>>>(dst, cnt, NE);
    k_dinv<<<(NN + 255) / 256, 256, 0, stream>>>(cnt, dinv, NN);
    k_bsum<<<NBLK, 256, 0, stream>>>(cnt, bsum);
    k_scan_bsum<<<1, 128, 0, stream>>>(bsum, row_ptr);
    k_scan_blocks<<<NBLK, 256, 0, stream>>>(cnt, bsum, row_ptr, cursor);
    k_fillslots<<<(NE + 255) / 256, 256, 0, stream>>>(src, dst, dinv, cursor, src_s, w_s, NE);

    // layer 1 (fused gather + GEMM)
    k_l1_fused<<<(NN + 63) / 64, 256, 0, stream>>>(x, row_ptr, src_s, w_s, dinv, W1, b1, h1);

    // layer 2 (fused gather + GEMM + pool)
    k_fill<<<(NG * 256 + 255) / 256, 256, 0, stream>>>((float*)gmax, 0.0f, NG * 256);
    k_l2_fused<<<(NN + 63) / 64, 256, 0, stream>>>(h1, row_ptr, src_s, w_s, dinv, W2, b2, batch, gmax);

    // MLP head
    k_gemm3<<<NG, 256, 0, stream>>>((const float*)gmax, Wg1, bg1, g1);
    k_gemm4<<<NG, 128, 0, stream>>>(g1, Wg2, bg2, (float*)d_out);
}

// Round 4
// 863.490 us; speedup vs baseline: 1.8105x; 1.8105x over previous
//
#include <hip/hip_runtime.h>
#include <hip/hip_bf16.h>

// GCN forward, CSR-gather formulation (unfused: gathers need full occupancy
// for latency hiding; GEMMs are LDS/register-tiled with VGPR pressure kept
// ~80 so the compiler's occupancy heuristic cannot spill accumulators).

#define NN 100000
#define NE 1600000
#define NG 512
#define NBLK ((NN + 1023) / 1024)   // 98 scan blocks

// ---------------- CSR build (counting sort by dst) ----------------

__global__ void k_zero_int(int* p, int n) {
    int i = blockIdx.x * blockDim.x + threadIdx.x;
    if (i < n) p[i] = 0;
}

__global__ void k_fill(float* p, float v, int n) {
    int i = blockIdx.x * blockDim.x + threadIdx.x;
    if (i < n) p[i] = v;
}

__global__ void k_hist(const int* __restrict__ dst, int* cnt, int e) {
    int i = blockIdx.x * blockDim.x + threadIdx.x;
    if (i < e) atomicAdd(&cnt[dst[i]], 1);
}

__global__ void k_dinv(const int* __restrict__ cnt, float* __restrict__ dinv, int n) {
    int i = blockIdx.x * blockDim.x + threadIdx.x;
    if (i < n) dinv[i] = rsqrtf((float)cnt[i] + 1.0f);
}

__global__ __launch_bounds__(256) void k_bsum(const int* __restrict__ cnt, int* __restrict__ bsum) {
    __shared__ int s[256];
    int b = blockIdx.x, t = threadIdx.x;
    int base = b * 1024 + t * 4;
    int v = 0;
#pragma unroll
    for (int j = 0; j < 4; j++) { int i = base + j; if (i < NN) v += cnt[i]; }
    s[t] = v; __syncthreads();
    for (int off = 128; off > 0; off >>= 1) {
        if (t < off) s[t] += s[t + off];
        __syncthreads();
    }
    if (t == 0) bsum[b] = s[0];
}

__global__ __launch_bounds__(128) void k_scan_bsum(int* bsum, int* row_ptr) {
    __shared__ int s[128];
    int t = threadIdx.x;
    int v = (t < NBLK) ? bsum[t] : 0;
    s[t] = v; __syncthreads();
    for (int off = 1; off < 128; off <<= 1) {
        int u = (t >= off) ? s[t - off] : 0;
        __syncthreads();
        s[t] += u;
        __syncthreads();
    }
    if (t < NBLK) bsum[t] = s[t] - v;
    if (t == 0) row_ptr[NN] = NE;
}

__global__ __launch_bounds__(256) void k_scan_blocks(const int* __restrict__ cnt,
    const int* __restrict__ bsum, int* __restrict__ row_ptr, int* __restrict__ cursor) {
    __shared__ int s[256];
    int b = blockIdx.x, t = threadIdx.x;
    int base = b * 1024 + t * 4;
    int v[4]; int sum = 0;
#pragma unroll
    for (int j = 0; j < 4; j++) { int i = base + j; v[j] = (i < NN) ? cnt[i] : 0; sum += v[j]; }
    s[t] = sum; __syncthreads();
    for (int off = 1; off < 256; off <<= 1) {
        int u = (t >= off) ? s[t - off] : 0;
        __syncthreads();
        s[t] += u;
        __syncthreads();
    }
    int excl = s[t] - sum + bsum[b];
#pragma unroll
    for (int j = 0; j < 4; j++) {
        int i = base + j;
        if (i < NN) { row_ptr[i] = excl; cursor[i] = excl; excl += v[j]; }
    }
}

__global__ void k_fillslots(const int* __restrict__ src, const int* __restrict__ dst,
    const float* __restrict__ dinv, int* cursor,
    int* __restrict__ src_s, float* __restrict__ w_s, int e) {
    int i = blockIdx.x * blockDim.x + threadIdx.x;
    if (i >= e) return;
    int s = src[i], d = dst[i];
    int pos = atomicAdd(&cursor[d], 1);
    src_s[pos] = s;
    w_s[pos] = dinv[s] * dinv[d];
}

// ---------------- gathers: one wave per node, full occupancy ----------------

__global__ __launch_bounds__(256) void k_gather78(const float* __restrict__ h,
    const int* __restrict__ rp, const int* __restrict__ src_s, const float* __restrict__ w_s,
    const float* __restrict__ dinv, float* __restrict__ agg) {
    int n = blockIdx.x * 4 + (threadIdx.x >> 6);
    if (n >= NN) return;
    int l = threadIdx.x & 63;
    float di = dinv[n], sw = di * di;
    const float* hn = h + (size_t)n * 78;
    float a0 = hn[l] * sw;
    float a1 = (l < 14) ? hn[64 + l] * sw : 0.0f;
    int e = rp[n], e1 = rp[n + 1];
    for (; e + 3 < e1; e += 4) {
        int s0 = src_s[e], s1 = src_s[e + 1], s2 = src_s[e + 2], s3 = src_s[e + 3];
        float w0 = w_s[e], w1 = w_s[e + 1], w2 = w_s[e + 2], w3 = w_s[e + 3];
        const float* p0 = h + (size_t)s0 * 78;
        const float* p1 = h + (size_t)s1 * 78;
        const float* p2 = h + (size_t)s2 * 78;
        const float* p3 = h + (size_t)s3 * 78;
        a0 += p0[l] * w0 + p1[l] * w1 + p2[l] * w2 + p3[l] * w3;
        if (l < 14) a1 += p0[64 + l] * w0 + p1[64 + l] * w1 + p2[64 + l] * w2 + p3[64 + l] * w3;
    }
    for (; e < e1; e++) {
        int s0 = src_s[e]; float w0 = w_s[e];
        const float* p0 = h + (size_t)s0 * 78;
        a0 += p0[l] * w0;
        if (l < 14) a1 += p0[64 + l] * w0;
    }
    float* an = agg + (size_t)n * 78;
    an[l] = a0;
    if (l < 14) an[64 + l] = a1;
}

__global__ __launch_bounds__(256) void k_gather128(const float* __restrict__ h,
    const int* __restrict__ rp, const int* __restrict__ src_s, const float* __restrict__ w_s,
    const float* __restrict__ dinv, float* __restrict__ agg) {
    int n = blockIdx.x * 4 + (threadIdx.x >> 6);
    if (n >= NN) return;
    int l = threadIdx.x & 63;
    float di = dinv[n], sw = di * di;
    float2 hv = ((const float2*)(h + (size_t)n * 128))[l];
    float ax = hv.x * sw, ay = hv.y * sw;
    int e = rp[n], e1 = rp[n + 1];
    for (; e + 3 < e1; e += 4) {
        int s0 = src_s[e], s1 = src_s[e + 1], s2 = src_s[e + 2], s3 = src_s[e + 3];
        float w0 = w_s[e], w1 = w_s[e + 1], w2 = w_s[e + 2], w3 = w_s[e + 3];
        float2 v0 = ((const float2*)(h + (size_t)s0 * 128))[l];
        float2 v1 = ((const float2*)(h + (size_t)s1 * 128))[l];
        float2 v2 = ((const float2*)(h + (size_t)s2 * 128))[l];
        float2 v3 = ((const float2*)(h + (size_t)s3 * 128))[l];
        ax += v0.x * w0 + v1.x * w1 + v2.x * w2 + v3.x * w3;
        ay += v0.y * w0 + v1.y * w1 + v2.y * w2 + v3.y * w3;
    }
    for (; e < e1; e++) {
        int s0 = src_s[e]; float w0 = w_s[e];
        float2 v0 = ((const float2*)(h + (size_t)s0 * 128))[l];
        ax += v0.x * w0; ay += v0.y * w0;
    }
    float2 o; o.x = ax; o.y = ay;
    ((float2*)(agg + (size_t)n * 128))[l] = o;
}

// ---------------- gemm1: h1 = relu(agg1[N,78] @ W1[78,128] + b1) ----------------
// 256 thr = 32tx(x4f=128) x 8ty(x8n=64 nodes); acc = 8 x float4 (32 VGPR).
__global__ __launch_bounds__(256) void k_gemm1(const float* __restrict__ A,
    const float* __restrict__ W, const float* __restrict__ bias,
    float* __restrict__ out) {
    __shared__ float As[64][80];    // 20.5 KB (k padded 78->80, zeros)
    __shared__ float Ws[40][128];   // 20 KB chunk (2 chunks of 40 k)
    int tid = threadIdx.x;
    int n0 = blockIdx.x * 64;
    for (int i = tid; i < 64 * 80; i += 256) {
        int row = i / 80, col = i - row * 80;
        int n = n0 + row;
        As[row][col] = (col < 78 && n < NN) ? A[(size_t)n * 78 + col] : 0.0f;
    }
    int tx = tid & 31, ty = tid >> 5;
    int f0 = tx * 4;
    float4 acc[8];
#pragma unroll
    for (int i = 0; i < 8; i++) acc[i] = make_float4(0.f, 0.f, 0.f, 0.f);

    for (int c = 0; c < 2; c++) {
        int k0 = c * 40;
        __syncthreads();   // c=0: As staged; c>0: prev Ws consumed
        for (int i = tid; i < 40 * 32; i += 256) {   // 1280 float4
            int k = i >> 5, f4 = (i & 31) << 2;
            int kg = k0 + k;
            if (kg < 78)
                *(float4*)&Ws[k][f4] = *(const float4*)&W[(size_t)kg * 128 + f4];
            else
                *(float4*)&Ws[k][f4] = make_float4(0.f, 0.f, 0.f, 0.f);
        }
        __syncthreads();
#pragma unroll
        for (int kk = 0; kk < 40; kk += 4) {
            float4 w0 = *(const float4*)&Ws[kk + 0][f0];
            float4 w1 = *(const float4*)&Ws[kk + 1][f0];
            float4 w2 = *(const float4*)&Ws[kk + 2][f0];
            float4 w3 = *(const float4*)&Ws[kk + 3][f0];
#pragma unroll
            for (int i = 0; i < 8; i++) {
                float4 a = *(const float4*)&As[ty * 8 + i][k0 + kk];
                acc[i].x += a.x * w0.x + a.y * w1.x + a.z * w2.x + a.w * w3.x;
                acc[i].y += a.x * w0.y + a.y * w1.y + a.z * w2.y + a.w * w3.y;
                acc[i].z += a.x * w0.z + a.y * w1.z + a.z * w2.z + a.w * w3.z;
                acc[i].w += a.x * w0.w + a.y * w1.w + a.z * w2.w + a.w * w3.w;
            }
        }
    }

    float4 bv = *(const float4*)&bias[f0];
#pragma unroll
    for (int i = 0; i < 8; i++) {
        int n = n0 + ty * 8 + i;
        if (n < NN) {
            float4 o;
            o.x = fmaxf(acc[i].x + bv.x, 0.f);
            o.y = fmaxf(acc[i].y + bv.y, 0.f);
            o.z = fmaxf(acc[i].z + bv.z, 0.f);
            o.w = fmaxf(acc[i].w + bv.w, 0.f);
            *(float4*)&out[(size_t)n * 128 + f0] = o;
        }
    }
}

// ---------------- gemm2+pool: relu(agg2[N,128] @ W2[128,256] + b2) -> segmax ----------------
// 256 thr = 64tx(x4f=256) x 4ty(x8n=32 nodes); acc = 8 x float4 (32 VGPR).
// Pool pre-reduced: batch sorted -> flush-on-change, ~2 flushes/thread.
__global__ __launch_bounds__(256) void k_gemm2_pool(const float* __restrict__ A,
    const float* __restrict__ W, const float* __restrict__ bias,
    const int* __restrict__ batch, unsigned* __restrict__ gmax) {
    __shared__ float As[32][128];   // 16 KB
    __shared__ float Ws[16][256];   // 16 KB chunk (8 chunks of 16 k)
    int tid = threadIdx.x;
    int n0 = blockIdx.x * 32;       // NN % 32 == 0 -> exact
    for (int i = tid; i < 1024; i += 256) {   // 32x128 floats as float4
        int row = i >> 5, c4 = (i & 31) << 2;
        *(float4*)&As[row][c4] = *(const float4*)&A[(size_t)(n0 + row) * 128 + c4];
    }
    int tx = tid & 63, ty = tid >> 6;
    int f0 = tx * 4;
    float4 acc[8];
#pragma unroll
    for (int i = 0; i < 8; i++) acc[i] = make_float4(0.f, 0.f, 0.f, 0.f);

    for (int c = 0; c < 8; c++) {
        int k0 = c * 16;
        __syncthreads();   // c=0: As staged; c>0: prev Ws consumed
        for (int i = tid; i < 1024; i += 256) {   // 16x256 floats as float4
            int k = i >> 6, f4 = (i & 63) << 2;
            *(float4*)&Ws[k][f4] = *(const float4*)&W[(size_t)(k0 + k) * 256 + f4];
        }
        __syncthreads();
#pragma unroll
        for (int kk = 0; kk < 16; kk += 4) {
            float4 w0 = *(const float4*)&Ws[kk + 0][f0];
            float4 w1 = *(const float4*)&Ws[kk + 1][f0];
            float4 w2 = *(const float4*)&Ws[kk + 2][f0];
            float4 w3 = *(const float4*)&Ws[kk + 3][f0];
#pragma unroll
            for (int h = 0; h < 2; h++) {       // two halves of 4 nodes -> lower live-regs
                float4 a[4];
#pragma unroll
                for (int i = 0; i < 4; i++) a[i] = *(const float4*)&As[ty * 8 + h * 4 + i][k0 + kk];
#pragma unroll
                for (int i = 0; i < 4; i++) {
                    int o = h * 4 + i;
                    acc[o].x += a[i].x * w0.x + a[i].y * w1.x + a[i].z * w2.x + a[i].w * w3.x;
                    acc[o].y += a[i].x * w0.y + a[i].y * w1.y + a[i].z * w2.y + a[i].w * w3.y;
                    acc[o].z += a[i].x * w0.z + a[i].y * w1.z + a[i].z * w2.z + a[i].w * w3.z;
                    acc[o].w += a[i].x * w0.w + a[i].y * w1.w + a[i].z * w2.w + a[i].w * w3.w;
                }
            }
        }
    }

    // epilogue: bias + relu + flush-on-change segment max (batch sorted)
    float4 bv = *(const float4*)&bias[f0];
    int curg = -1;
    float4 m = make_float4(0.f, 0.f, 0.f, 0.f);
#pragma unroll
    for (int i = 0; i < 8; i++) {
        int n = n0 + ty * 8 + i;
        int g = batch[n];
        float4 v;
        v.x = fmaxf(acc[i].x + bv.x, 0.f); v.y = fmaxf(acc[i].y + bv.y, 0.f);
        v.z = fmaxf(acc[i].z + bv.z, 0.f); v.w = fmaxf(acc[i].w + bv.w, 0.f);
        if (g != curg) {
            if (curg >= 0) {
                unsigned* gp = &gmax[(size_t)curg * 256 + f0];
                atomicMax(&gp[0], __float_as_uint(m.x));
                atomicMax(&gp[1], __float_as_uint(m.y));
                atomicMax(&gp[2], __float_as_uint(m.z));
                atomicMax(&gp[3], __float_as_uint(m.w));
            }
            curg = g; m = v;
        } else {
            m.x = fmaxf(m.x, v.x); m.y = fmaxf(m.y, v.y);
            m.z = fmaxf(m.z, v.z); m.w = fmaxf(m.w, v.w);
        }
    }
    if (curg >= 0) {
        unsigned* gp = &gmax[(size_t)curg * 256 + f0];
        atomicMax(&gp[0], __float_as_uint(m.x));
        atomicMax(&gp[1], __float_as_uint(m.y));
        atomicMax(&gp[2], __float_as_uint(m.z));
        atomicMax(&gp[3], __float_as_uint(m.w));
    }
}

// ---------------- MLP head ----------------

__global__ __launch_bounds__(256) void k_gemm3(const float* __restrict__ A,
    const float* __restrict__ W, const float* __restrict__ bias,
    float* __restrict__ out) {
    __shared__ float rs[256];
    int g = blockIdx.x, tid = threadIdx.x;
    rs[tid] = A[g * 256 + tid];
    __syncthreads();
    float acc[4] = {0.f, 0.f, 0.f, 0.f};
    for (int k = 0; k < 256; k++) {
        float a = rs[k];
#pragma unroll
        for (int j = 0; j < 4; j++) acc[j] += a * W[k * 1024 + tid + j * 256];
    }
#pragma unroll
    for (int j = 0; j < 4; j++) {
        int f = tid + j * 256;
        out[g * 1024 + f] = fmaxf(acc[j] + bias[f], 0.0f);
    }
}

__global__ __launch_bounds__(128) void k_gemm4(const float* __restrict__ A,
    const float* __restrict__ W, const float* __restrict__ bias,
    float* __restrict__ out) {
    __shared__ float rs[1024];
    int g = blockIdx.x, tid = threadIdx.x;
    for (int i = tid; i < 1024; i += 128) rs[i] = A[g * 1024 + i];
    __syncthreads();
    float acc = 0.0f;
    for (int k = 0; k < 1024; k++) acc += rs[k] * W[k * 128 + tid];
    out[g * 128 + tid] = acc + bias[tid];
}

extern "C" void kernel_launch(void* const* d_in, const int* in_sizes, int n_in,
                              void* d_out, int out_size, void* d_ws, size_t ws_size,
                              hipStream_t stream) {
    const float* x    = (const float*)d_in[0];
    const int*   ei   = (const int*)d_in[1];
    const int*   batch= (const int*)d_in[2];
    const float* W1   = (const float*)d_in[3];
    const float* b1   = (const float*)d_in[4];
    const float* W2   = (const float*)d_in[5];
    const float* b2   = (const float*)d_in[6];
    const float* Wg1  = (const float*)d_in[7];
    const float* bg1  = (const float*)d_in[8];
    const float* Wg2  = (const float*)d_in[9];
    const float* bg2  = (const float*)d_in[10];
    const int* src = ei;
    const int* dst = ei + NE;

    char* w8 = (char*)d_ws;
    int*   cnt     = (int*)w8;                 w8 += (size_t)NN * 4;
    int*   row_ptr = (int*)w8;                 w8 += (size_t)(NN + 4) * 4;
    int*   cursor  = (int*)w8;                 w8 += (size_t)NN * 4;
    int*   bsum    = (int*)w8;                 w8 += 128 * 4;
    int*   src_s   = (int*)w8;                 w8 += (size_t)NE * 4;
    float* w_s     = (float*)w8;               w8 += (size_t)NE * 4;
    float* dinv    = (float*)w8;               w8 += (size_t)NN * 4;
    float* agg1    = (float*)w8;               w8 += (size_t)NN * 78 * 4;
    float* h1      = (float*)w8;               w8 += (size_t)NN * 128 * 4;
    float* agg2    = (float*)w8;               w8 += (size_t)NN * 128 * 4;
    unsigned* gmax = (unsigned*)w8;            w8 += (size_t)NG * 256 * 4;
    float* g1      = (float*)w8;               w8 += (size_t)NG * 1024 * 4;

    // CSR build
    k_zero_int<<<(NN + 255) / 256, 256, 0, stream>>>(cnt, NN);
    k_hist<<<(NE + 255) / 256, 256, 0, stream>>>(dst, cnt, NE);
    k_dinv<<<(NN + 255) / 256, 256, 0, stream>>>(cnt, dinv, NN);
    k_bsum<<<NBLK, 256, 0, stream>>>(cnt, bsum);
    k_scan_bsum<<<1, 128, 0, stream>>>(bsum, row_ptr);
    k_scan_blocks<<<NBLK, 256, 0, stream>>>(cnt, bsum, row_ptr, cursor);
    k_fillslots<<<(NE + 255) / 256, 256, 0, stream>>>(src, dst, dinv, cursor, src_s, w_s, NE);

    // layer 1
    k_gather78<<<(NN + 3) / 4, 256, 0, stream>>>(x, row_ptr, src_s, w_s, dinv, agg1);
    k_gemm1<<<(NN + 63) / 64, 256, 0, stream>>>(agg1, W1, b1, h1);

    // layer 2
    k_gather128<<<(NN + 3) / 4, 256, 0, stream>>>(h1, row_ptr, src_s, w_s, dinv, agg2);
    k_fill<<<(NG * 256 + 255) / 256, 256, 0, stream>>>((float*)gmax, 0.0f, NG * 256);
    k_gemm2_pool<<<NN / 32, 256, 0, stream>>>(agg2, W2, b2, batch, gmax);

    // MLP head
    k_gemm3<<<NG, 256, 0, stream>>>((const float*)gmax, Wg1, bg1, g1);
    k_gemm4<<<NG, 128, 0, stream>>>(g1, Wg2, bg2, (float*)d_out);
}

// Round 5
// 757.375 us; speedup vs baseline: 2.0641x; 1.1401x over previous
//
#include <hip/hip_runtime.h>
#include <hip/hip_bf16.h>

// GCN forward, CSR-gather formulation.
// GEMMs: W staged in LDS (the only LDS-pipe consumer); A-operand read via
// wave-uniform global/scalar loads (readfirstlane) -> VALU-bound, not LDS-bound
// (round-4 was ds_read_b128-issue-bound at VALUBusy 41%).
// Gathers: minimal load-instruction count per edge row (float2 / half-wave float4).

#define NN 100000
#define NE 1600000
#define NG 512
#define NBLK ((NN + 1023) / 1024)   // 98 scan blocks

// ---------------- CSR build (counting sort by dst) ----------------

__global__ void k_zero_int(int* p, int n) {
    int i = blockIdx.x * blockDim.x + threadIdx.x;
    if (i < n) p[i] = 0;
}

__global__ void k_fill(float* p, float v, int n) {
    int i = blockIdx.x * blockDim.x + threadIdx.x;
    if (i < n) p[i] = v;
}

__global__ void k_hist(const int* __restrict__ dst, int* cnt, int e) {
    int i = blockIdx.x * blockDim.x + threadIdx.x;
    if (i < e) atomicAdd(&cnt[dst[i]], 1);
}

__global__ void k_dinv(const int* __restrict__ cnt, float* __restrict__ dinv, int n) {
    int i = blockIdx.x * blockDim.x + threadIdx.x;
    if (i < n) dinv[i] = rsqrtf((float)cnt[i] + 1.0f);
}

__global__ __launch_bounds__(256) void k_bsum(const int* __restrict__ cnt, int* __restrict__ bsum) {
    __shared__ int s[256];
    int b = blockIdx.x, t = threadIdx.x;
    int base = b * 1024 + t * 4;
    int v = 0;
#pragma unroll
    for (int j = 0; j < 4; j++) { int i = base + j; if (i < NN) v += cnt[i]; }
    s[t] = v; __syncthreads();
    for (int off = 128; off > 0; off >>= 1) {
        if (t < off) s[t] += s[t + off];
        __syncthreads();
    }
    if (t == 0) bsum[b] = s[0];
}

__global__ __launch_bounds__(128) void k_scan_bsum(int* bsum, int* row_ptr) {
    __shared__ int s[128];
    int t = threadIdx.x;
    int v = (t < NBLK) ? bsum[t] : 0;
    s[t] = v; __syncthreads();
    for (int off = 1; off < 128; off <<= 1) {
        int u = (t >= off) ? s[t - off] : 0;
        __syncthreads();
        s[t] += u;
        __syncthreads();
    }
    if (t < NBLK) bsum[t] = s[t] - v;
    if (t == 0) row_ptr[NN] = NE;
}

__global__ __launch_bounds__(256) void k_scan_blocks(const int* __restrict__ cnt,
    const int* __restrict__ bsum, int* __restrict__ row_ptr, int* __restrict__ cursor) {
    __shared__ int s[256];
    int b = blockIdx.x, t = threadIdx.x;
    int base = b * 1024 + t * 4;
    int v[4]; int sum = 0;
#pragma unroll
    for (int j = 0; j < 4; j++) { int i = base + j; v[j] = (i < NN) ? cnt[i] : 0; sum += v[j]; }
    s[t] = sum; __syncthreads();
    for (int off = 1; off < 256; off <<= 1) {
        int u = (t >= off) ? s[t - off] : 0;
        __syncthreads();
        s[t] += u;
        __syncthreads();
    }
    int excl = s[t] - sum + bsum[b];
#pragma unroll
    for (int j = 0; j < 4; j++) {
        int i = base + j;
        if (i < NN) { row_ptr[i] = excl; cursor[i] = excl; excl += v[j]; }
    }
}

__global__ void k_fillslots(const int* __restrict__ src, const int* __restrict__ dst,
    const float* __restrict__ dinv, int* cursor,
    int* __restrict__ src_s, float* __restrict__ w_s, int e) {
    int i = blockIdx.x * blockDim.x + threadIdx.x;
    if (i >= e) return;
    int s = src[i], d = dst[i];
    int pos = atomicAdd(&cursor[d], 1);
    src_s[pos] = s;
    w_s[pos] = dinv[s] * dinv[d];
}

// ---------------- gather78: one wave per node, float2 per lane (39 active) ----------------
// Output agg1 has row stride 80 (cols 78,79 left as-is; gemm1 multiplies them by 0).
__global__ __launch_bounds__(256) void k_gather78(const float* __restrict__ h,
    const int* __restrict__ rp, const int* __restrict__ src_s, const float* __restrict__ w_s,
    const float* __restrict__ dinv, float* __restrict__ agg) {
    int n = blockIdx.x * 4 + (threadIdx.x >> 6);
    int l = threadIdx.x & 63;
    if (l >= 39) return;              // 39 lanes x float2 = 78 floats
    float di = dinv[n], sw = di * di;
    float2 a = ((const float2*)(h + (size_t)n * 78))[l];
    a.x *= sw; a.y *= sw;
    int e = rp[n], e1 = rp[n + 1];
    for (; e + 3 < e1; e += 4) {
        int s0 = src_s[e], s1 = src_s[e + 1], s2 = src_s[e + 2], s3 = src_s[e + 3];
        float w0 = w_s[e], w1 = w_s[e + 1], w2 = w_s[e + 2], w3 = w_s[e + 3];
        float2 v0 = ((const float2*)(h + (size_t)s0 * 78))[l];
        float2 v1 = ((const float2*)(h + (size_t)s1 * 78))[l];
        float2 v2 = ((const float2*)(h + (size_t)s2 * 78))[l];
        float2 v3 = ((const float2*)(h + (size_t)s3 * 78))[l];
        a.x += v0.x * w0 + v1.x * w1 + v2.x * w2 + v3.x * w3;
        a.y += v0.y * w0 + v1.y * w1 + v2.y * w2 + v3.y * w3;
    }
    for (; e < e1; e++) {
        int s0 = src_s[e]; float w0 = w_s[e];
        float2 v0 = ((const float2*)(h + (size_t)s0 * 78))[l];
        a.x += v0.x * w0; a.y += v0.y * w0;
    }
    agg[(size_t)n * 80 + 2 * l]     = a.x;
    agg[(size_t)n * 80 + 2 * l + 1] = a.y;
}

// ---------------- gather128: half-wave per node, float4 per lane ----------------
// 256 thr = 4 waves x 2 half-waves -> 8 nodes/block. One b128 instr covers 2 rows.
__global__ __launch_bounds__(256) void k_gather128(const float* __restrict__ h,
    const int* __restrict__ rp, const int* __restrict__ src_s, const float* __restrict__ w_s,
    const float* __restrict__ dinv, float* __restrict__ agg) {
    int tid = threadIdx.x;
    int n = blockIdx.x * 8 + (tid >> 5);   // 2 nodes per wave
    int l = tid & 31;                      // 32 lanes x float4 = 128 floats
    float di = dinv[n], sw = di * di;
    float4 a = ((const float4*)(h + (size_t)n * 128))[l];
    a.x *= sw; a.y *= sw; a.z *= sw; a.w *= sw;
    int e = rp[n], e1 = rp[n + 1];
    for (; e + 3 < e1; e += 4) {
        int s0 = src_s[e], s1 = src_s[e + 1], s2 = src_s[e + 2], s3 = src_s[e + 3];
        float w0 = w_s[e], w1 = w_s[e + 1], w2 = w_s[e + 2], w3 = w_s[e + 3];
        float4 v0 = ((const float4*)(h + (size_t)s0 * 128))[l];
        float4 v1 = ((const float4*)(h + (size_t)s1 * 128))[l];
        float4 v2 = ((const float4*)(h + (size_t)s2 * 128))[l];
        float4 v3 = ((const float4*)(h + (size_t)s3 * 128))[l];
        a.x += v0.x * w0 + v1.x * w1 + v2.x * w2 + v3.x * w3;
        a.y += v0.y * w0 + v1.y * w1 + v2.y * w2 + v3.y * w3;
        a.z += v0.z * w0 + v1.z * w1 + v2.z * w2 + v3.z * w3;
        a.w += v0.w * w0 + v1.w * w1 + v2.w * w2 + v3.w * w3;
    }
    for (; e < e1; e++) {
        int s0 = src_s[e]; float w0 = w_s[e];
        float4 v0 = ((const float4*)(h + (size_t)s0 * 128))[l];
        a.x += v0.x * w0; a.y += v0.y * w0; a.z += v0.z * w0; a.w += v0.w * w0;
    }
    ((float4*)(agg + (size_t)n * 128))[l] = a;
}

// ---------------- gemm1: h1 = relu(agg1[N,80-stride] @ W1[78,128] + b1) ----------------
// W1 fully LDS-resident (80x128, rows 78/79 zero). One sync, then each wave
// independently computes 16 nodes; lane covers 2 feats; A via uniform loads.
__global__ __launch_bounds__(256) void k_gemm1(const float* __restrict__ A,
    const float* __restrict__ W, const float* __restrict__ bias,
    float* __restrict__ out) {
    __shared__ float Ws[80][128];   // 40 KB
    int tid = threadIdx.x;
    for (int i = tid; i < 80 * 128; i += 256) {
        int k = i >> 7, f = i & 127;
        Ws[k][f] = (k < 78) ? W[k * 128 + f] : 0.0f;
    }
    __syncthreads();
    int wv = tid >> 6, l = tid & 63;
    int task = blockIdx.x * 4 + wv;
    if (task >= NN / 16) return;    // 6250 tasks
    task = __builtin_amdgcn_readfirstlane(task);
    int n0 = task * 16;
    const float* a0p = A + (size_t)n0 * 80;
    int f0 = l * 2;
    float2 acc[16];
#pragma unroll
    for (int i = 0; i < 16; i++) acc[i] = make_float2(0.f, 0.f);

    for (int k = 0; k < 80; k += 4) {
        float2 w0 = *(const float2*)&Ws[k + 0][f0];
        float2 w1 = *(const float2*)&Ws[k + 1][f0];
        float2 w2 = *(const float2*)&Ws[k + 2][f0];
        float2 w3 = *(const float2*)&Ws[k + 3][f0];
#pragma unroll
        for (int i = 0; i < 16; i++) {
            float4 a = *(const float4*)(a0p + (size_t)i * 80 + k);
            acc[i].x += a.x * w0.x + a.y * w1.x + a.z * w2.x + a.w * w3.x;
            acc[i].y += a.x * w0.y + a.y * w1.y + a.z * w2.y + a.w * w3.y;
        }
    }
    float2 bv = *(const float2*)&bias[f0];
#pragma unroll
    for (int i = 0; i < 16; i++) {
        float2 o;
        o.x = fmaxf(acc[i].x + bv.x, 0.f);
        o.y = fmaxf(acc[i].y + bv.y, 0.f);
        *(float2*)&out[(size_t)(n0 + i) * 128 + f0] = o;
    }
}

// ---------------- gemm2+pool: relu(agg2[N,128] @ W2[128,256] + b2) -> segmax ----------------
// 256 thr = 4 waves; each wave owns 8 nodes; lane covers 4 feats (64x4=256).
// W2 staged in 16-k LDS chunks (16 KB); A via wave-uniform global loads ->
// LDS pipe carries only W (16 b128/chunk/wave) -> VALU-bound.
__global__ __launch_bounds__(256) void k_gemm2_pool(const float* __restrict__ A,
    const float* __restrict__ W, const float* __restrict__ bias,
    const int* __restrict__ batch, unsigned* __restrict__ gmax) {
    __shared__ float Ws[16][256];   // 16 KB
    int tid = threadIdx.x;
    int wv = tid >> 6, l = tid & 63;
    int task = __builtin_amdgcn_readfirstlane(blockIdx.x * 4 + wv);  // 12500 tasks exact
    int n0 = task * 8;
    const float* a0p = A + (size_t)n0 * 128;
    int f0 = l * 4;
    float4 acc[8];
#pragma unroll
    for (int i = 0; i < 8; i++) acc[i] = make_float4(0.f, 0.f, 0.f, 0.f);

    for (int c = 0; c < 8; c++) {
        int k0 = c * 16;
        __syncthreads();
        for (int i = tid; i < 1024; i += 256) {   // 16x256 floats as float4
            int k = i >> 6, f4 = (i & 63) << 2;
            *(float4*)&Ws[k][f4] = *(const float4*)&W[(size_t)(k0 + k) * 256 + f4];
        }
        __syncthreads();
#pragma unroll
        for (int kk = 0; kk < 16; kk += 4) {
            float4 w0 = *(const float4*)&Ws[kk + 0][f0];
            float4 w1 = *(const float4*)&Ws[kk + 1][f0];
            float4 w2 = *(const float4*)&Ws[kk + 2][f0];
            float4 w3 = *(const float4*)&Ws[kk + 3][f0];
#pragma unroll
            for (int i = 0; i < 8; i++) {
                float4 a = *(const float4*)(a0p + (size_t)i * 128 + k0 + kk);
                acc[i].x += a.x * w0.x + a.y * w1.x + a.z * w2.x + a.w * w3.x;
                acc[i].y += a.x * w0.y + a.y * w1.y + a.z * w2.y + a.w * w3.y;
                acc[i].z += a.x * w0.z + a.y * w1.z + a.z * w2.z + a.w * w3.z;
                acc[i].w += a.x * w0.w + a.y * w1.w + a.z * w2.w + a.w * w3.w;
            }
        }
    }

    // epilogue: bias + relu + flush-on-change segment max (batch sorted)
    float4 bv = *(const float4*)&bias[f0];
    int curg = -1;
    float4 m = make_float4(0.f, 0.f, 0.f, 0.f);
#pragma unroll
    for (int i = 0; i < 8; i++) {
        int g = batch[n0 + i];
        float4 v;
        v.x = fmaxf(acc[i].x + bv.x, 0.f); v.y = fmaxf(acc[i].y + bv.y, 0.f);
        v.z = fmaxf(acc[i].z + bv.z, 0.f); v.w = fmaxf(acc[i].w + bv.w, 0.f);
        if (g != curg) {
            if (curg >= 0) {
                unsigned* gp = &gmax[(size_t)curg * 256 + f0];
                atomicMax(&gp[0], __float_as_uint(m.x));
                atomicMax(&gp[1], __float_as_uint(m.y));
                atomicMax(&gp[2], __float_as_uint(m.z));
                atomicMax(&gp[3], __float_as_uint(m.w));
            }
            curg = g; m = v;
        } else {
            m.x = fmaxf(m.x, v.x); m.y = fmaxf(m.y, v.y);
            m.z = fmaxf(m.z, v.z); m.w = fmaxf(m.w, v.w);
        }
    }
    if (curg >= 0) {
        unsigned* gp = &gmax[(size_t)curg * 256 + f0];
        atomicMax(&gp[0], __float_as_uint(m.x));
        atomicMax(&gp[1], __float_as_uint(m.y));
        atomicMax(&gp[2], __float_as_uint(m.z));
        atomicMax(&gp[3], __float_as_uint(m.w));
    }
}

// ---------------- MLP head ----------------

__global__ __launch_bounds__(256) void k_gemm3(const float* __restrict__ A,
    const float* __restrict__ W, const float* __restrict__ bias,
    float* __restrict__ out) {
    __shared__ float rs[256];
    int g = blockIdx.x, tid = threadIdx.x;
    rs[tid] = A[g * 256 + tid];
    __syncthreads();
    float acc[4] = {0.f, 0.f, 0.f, 0.f};
    for (int k = 0; k < 256; k++) {
        float a = rs[k];
#pragma unroll
        for (int j = 0; j < 4; j++) acc[j] += a * W[k * 1024 + tid + j * 256];
    }
#pragma unroll
    for (int j = 0; j < 4; j++) {
        int f = tid + j * 256;
        out[g * 1024 + f] = fmaxf(acc[j] + bias[f], 0.0f);
    }
}

__global__ __launch_bounds__(128) void k_gemm4(const float* __restrict__ A,
    const float* __restrict__ W, const float* __restrict__ bias,
    float* __restrict__ out) {
    __shared__ float rs[1024];
    int g = blockIdx.x, tid = threadIdx.x;
    for (int i = tid; i < 1024; i += 128) rs[i] = A[g * 1024 + i];
    __syncthreads();
    float acc = 0.0f;
    for (int k = 0; k < 1024; k++) acc += rs[k] * W[k * 128 + tid];
    out[g * 128 + tid] = acc + bias[tid];
}

extern "C" void kernel_launch(void* const* d_in, const int* in_sizes, int n_in,
                              void* d_out, int out_size, void* d_ws, size_t ws_size,
                              hipStream_t stream) {
    const float* x    = (const float*)d_in[0];
    const int*   ei   = (const int*)d_in[1];
    const int*   batch= (const int*)d_in[2];
    const float* W1   = (const float*)d_in[3];
    const float* b1   = (const float*)d_in[4];
    const float* W2   = (const float*)d_in[5];
    const float* b2   = (const float*)d_in[6];
    const float* Wg1  = (const float*)d_in[7];
    const float* bg1  = (const float*)d_in[8];
    const float* Wg2  = (const float*)d_in[9];
    const float* bg2  = (const float*)d_in[10];
    const int* src = ei;
    const int* dst = ei + NE;

    char* w8 = (char*)d_ws;
    int*   cnt     = (int*)w8;                 w8 += (size_t)NN * 4;
    int*   row_ptr = (int*)w8;                 w8 += (size_t)(NN + 4) * 4;
    int*   cursor  = (int*)w8;                 w8 += (size_t)NN * 4;
    int*   bsum    = (int*)w8;                 w8 += 128 * 4;
    int*   src_s   = (int*)w8;                 w8 += (size_t)NE * 4;
    float* w_s     = (float*)w8;               w8 += (size_t)NE * 4;
    float* dinv    = (float*)w8;               w8 += (size_t)NN * 4;
    float* agg1    = (float*)w8;               w8 += (size_t)NN * 80 * 4;   // stride 80
    float* h1      = (float*)w8;               w8 += (size_t)NN * 128 * 4;
    float* agg2    = (float*)w8;               w8 += (size_t)NN * 128 * 4;
    unsigned* gmax = (unsigned*)w8;            w8 += (size_t)NG * 256 * 4;
    float* g1      = (float*)w8;               w8 += (size_t)NG * 1024 * 4;

    // CSR build
    k_zero_int<<<(NN + 255) / 256, 256, 0, stream>>>(cnt, NN);
    k_hist<<<(NE + 255) / 256, 256, 0, stream>>>(dst, cnt, NE);
    k_dinv<<<(NN + 255) / 256, 256, 0, stream>>>(cnt, dinv, NN);
    k_bsum<<<NBLK, 256, 0, stream>>>(cnt, bsum);
    k_scan_bsum<<<1, 128, 0, stream>>>(bsum, row_ptr);
    k_scan_blocks<<<NBLK, 256, 0, stream>>>(cnt, bsum, row_ptr, cursor);
    k_fillslots<<<(NE + 255) / 256, 256, 0, stream>>>(src, dst, dinv, cursor, src_s, w_s, NE);

    // layer 1
    k_gather78<<<NN / 4, 256, 0, stream>>>(x, row_ptr, src_s, w_s, dinv, agg1);
    k_gemm1<<<(NN / 16 + 3) / 4, 256, 0, stream>>>(agg1, W1, b1, h1);

    // layer 2
    k_gather128<<<NN / 8, 256, 0, stream>>>(h1, row_ptr, src_s, w_s, dinv, agg2);
    k_fill<<<(NG * 256 + 255) / 256, 256, 0, stream>>>((float*)gmax, 0.0f, NG * 256);
    k_gemm2_pool<<<NN / 32, 256, 0, stream>>>(agg2, W2, b2, batch, gmax);

    // MLP head
    k_gemm3<<<NG, 256, 0, stream>>>((const float*)gmax, Wg1, bg1, g1);
    k_gemm4<<<NG, 128, 0, stream>>>(g1, Wg2, bg2, (float*)d_out);
}

// Round 6
// 749.031 us; speedup vs baseline: 2.0871x; 1.0111x over previous
//
#include <hip/hip_runtime.h>
#include <hip/hip_bf16.h>

// GCN forward, CSR-gather formulation.
// Gathers: one wave per node (uniform edge loop), 8-deep software-pipelined
//   unroll with prefetched packed (src,w) int2 edges -> max outstanding loads.
// GEMMs: W staged in LDS; A via wave-uniform (scalar) loads.
// gemm2 fuses bias+ReLU+pre-reduced segment-max pooling (batch sorted).

#define NN 100000
#define NE 1600000
#define NG 512
#define NBLK ((NN + 1023) / 1024)   // 98 scan blocks

// ---------------- CSR build (counting sort by dst) ----------------

__global__ void k_zero_int(int* p, int n) {
    int i = blockIdx.x * blockDim.x + threadIdx.x;
    if (i < n) p[i] = 0;
}

__global__ void k_hist(const int* __restrict__ dst, int* cnt, int e) {
    int i = blockIdx.x * blockDim.x + threadIdx.x;
    if (i < e) atomicAdd(&cnt[dst[i]], 1);
}

// fused: dinv[i] = rsqrt(cnt[i]+1)  and  gmax zero-init (NG*256 = 131072)
__global__ void k_prep(const int* __restrict__ cnt, float* __restrict__ dinv,
                       float* __restrict__ gmax) {
    int i = blockIdx.x * blockDim.x + threadIdx.x;
    if (i < NN) dinv[i] = rsqrtf((float)cnt[i] + 1.0f);
    if (i < NG * 256) gmax[i] = 0.0f;
}

__global__ __launch_bounds__(256) void k_bsum(const int* __restrict__ cnt, int* __restrict__ bsum) {
    __shared__ int s[256];
    int b = blockIdx.x, t = threadIdx.x;
    int base = b * 1024 + t * 4;
    int v = 0;
#pragma unroll
    for (int j = 0; j < 4; j++) { int i = base + j; if (i < NN) v += cnt[i]; }
    s[t] = v; __syncthreads();
    for (int off = 128; off > 0; off >>= 1) {
        if (t < off) s[t] += s[t + off];
        __syncthreads();
    }
    if (t == 0) bsum[b] = s[0];
}

__global__ __launch_bounds__(128) void k_scan_bsum(int* bsum, int* row_ptr) {
    __shared__ int s[128];
    int t = threadIdx.x;
    int v = (t < NBLK) ? bsum[t] : 0;
    s[t] = v; __syncthreads();
    for (int off = 1; off < 128; off <<= 1) {
        int u = (t >= off) ? s[t - off] : 0;
        __syncthreads();
        s[t] += u;
        __syncthreads();
    }
    if (t < NBLK) bsum[t] = s[t] - v;
    if (t == 0) row_ptr[NN] = NE;
}

__global__ __launch_bounds__(256) void k_scan_blocks(const int* __restrict__ cnt,
    const int* __restrict__ bsum, int* __restrict__ row_ptr, int* __restrict__ cursor) {
    __shared__ int s[256];
    int b = blockIdx.x, t = threadIdx.x;
    int base = b * 1024 + t * 4;
    int v[4]; int sum = 0;
#pragma unroll
    for (int j = 0; j < 4; j++) { int i = base + j; v[j] = (i < NN) ? cnt[i] : 0; sum += v[j]; }
    s[t] = sum; __syncthreads();
    for (int off = 1; off < 256; off <<= 1) {
        int u = (t >= off) ? s[t - off] : 0;
        __syncthreads();
        s[t] += u;
        __syncthreads();
    }
    int excl = s[t] - sum + bsum[b];
#pragma unroll
    for (int j = 0; j < 4; j++) {
        int i = base + j;
        if (i < NN) { row_ptr[i] = excl; cursor[i] = excl; excl += v[j]; }
    }
}

// counting-sort fill: one packed 8B store per edge: es[pos] = {src, w}
__global__ void k_fillslots(const int* __restrict__ src, const int* __restrict__ dst,
    const float* __restrict__ dinv, int* cursor, int2* __restrict__ es, int e) {
    int i = blockIdx.x * blockDim.x + threadIdx.x;
    if (i >= e) return;
    int s = src[i], d = dst[i];
    int pos = atomicAdd(&cursor[d], 1);
    es[pos] = make_int2(s, __float_as_int(dinv[s] * dinv[d]));
}

// ---------------- gather78: one wave per node, float2 x 39 lanes ----------------
// agg1 row stride 80 (cols 78/79 garbage; gemm1's W rows 78/79 are zero).
__global__ __launch_bounds__(256) void k_gather78(const float* __restrict__ h,
    const int* __restrict__ rp, const int2* __restrict__ es,
    const float* __restrict__ dinv, float* __restrict__ agg) {
    int n = blockIdx.x * 4 + (threadIdx.x >> 6);
    int l = threadIdx.x & 63;
    if (l >= 39) return;
    float di = dinv[n], sw = di * di;
    float2 a = ((const float2*)(h + (size_t)n * 78))[l];
    a.x *= sw; a.y *= sw;
    int e = rp[n], e1 = rp[n + 1];
    int nf = (e1 - e) >> 3;
    if (nf > 0) {
        int2 cur[8];
#pragma unroll
        for (int j = 0; j < 8; j++) cur[j] = es[e + j];
        for (int b = 1; ; b++) {
            float2 v[8];
#pragma unroll
            for (int j = 0; j < 8; j++)
                v[j] = ((const float2*)(h + (size_t)cur[j].x * 78))[l];
            e += 8;
            bool more = (b < nf);
            int2 nxt[8];
            if (more) {
#pragma unroll
                for (int j = 0; j < 8; j++) nxt[j] = es[e + j];
            }
#pragma unroll
            for (int j = 0; j < 8; j++) {
                float w = __int_as_float(cur[j].y);
                a.x += v[j].x * w; a.y += v[j].y * w;
            }
            if (!more) break;
#pragma unroll
            for (int j = 0; j < 8; j++) cur[j] = nxt[j];
        }
    }
    for (; e < e1; e++) {
        int2 p = es[e];
        float w = __int_as_float(p.y);
        float2 v = ((const float2*)(h + (size_t)p.x * 78))[l];
        a.x += v.x * w; a.y += v.y * w;
    }
    *(float2*)&agg[(size_t)n * 80 + 2 * l] = a;
}

// ---------------- gather128: one wave per node, float2 x 64 lanes ----------------
__global__ __launch_bounds__(256) void k_gather128(const float* __restrict__ h,
    const int* __restrict__ rp, const int2* __restrict__ es,
    const float* __restrict__ dinv, float* __restrict__ agg) {
    int n = blockIdx.x * 4 + (threadIdx.x >> 6);
    int l = threadIdx.x & 63;
    float di = dinv[n], sw = di * di;
    float2 a = ((const float2*)(h + (size_t)n * 128))[l];
    a.x *= sw; a.y *= sw;
    int e = rp[n], e1 = rp[n + 1];
    int nf = (e1 - e) >> 3;
    if (nf > 0) {
        int2 cur[8];
#pragma unroll
        for (int j = 0; j < 8; j++) cur[j] = es[e + j];
        for (int b = 1; ; b++) {
            float2 v[8];
#pragma unroll
            for (int j = 0; j < 8; j++)
                v[j] = ((const float2*)(h + (size_t)cur[j].x * 128))[l];
            e += 8;
            bool more = (b < nf);
            int2 nxt[8];
            if (more) {
#pragma unroll
                for (int j = 0; j < 8; j++) nxt[j] = es[e + j];
            }
#pragma unroll
            for (int j = 0; j < 8; j++) {
                float w = __int_as_float(cur[j].y);
                a.x += v[j].x * w; a.y += v[j].y * w;
            }
            if (!more) break;
#pragma unroll
            for (int j = 0; j < 8; j++) cur[j] = nxt[j];
        }
    }
    for (; e < e1; e++) {
        int2 p = es[e];
        float w = __int_as_float(p.y);
        float2 v = ((const float2*)(h + (size_t)p.x * 128))[l];
        a.x += v.x * w; a.y += v.y * w;
    }
    ((float2*)(agg + (size_t)n * 128))[l] = a;
}

// ---------------- gemm1: h1 = relu(agg1[N,80-stride] @ W1[78,128] + b1) ----------------
// W1 fully LDS-resident (80x128, rows 78/79 zero). Each wave: 16 nodes; lane
// covers 2 feats; A via wave-uniform (scalar) loads.
__global__ __launch_bounds__(256) void k_gemm1(const float* __restrict__ A,
    const float* __restrict__ W, const float* __restrict__ bias,
    float* __restrict__ out) {
    __shared__ float Ws[80][128];   // 40 KB
    int tid = threadIdx.x;
    for (int i = tid; i < 80 * 128; i += 256) {
        int k = i >> 7, f = i & 127;
        Ws[k][f] = (k < 78) ? W[k * 128 + f] : 0.0f;
    }
    __syncthreads();
    int wv = tid >> 6, l = tid & 63;
    int task = blockIdx.x * 4 + wv;
    if (task >= NN / 16) return;    // 6250 tasks
    task = __builtin_amdgcn_readfirstlane(task);
    int n0 = task * 16;
    const float* a0p = A + (size_t)n0 * 80;
    int f0 = l * 2;
    float2 acc[16];
#pragma unroll
    for (int i = 0; i < 16; i++) acc[i] = make_float2(0.f, 0.f);

    for (int k = 0; k < 80; k += 4) {
        float2 w0 = *(const float2*)&Ws[k + 0][f0];
        float2 w1 = *(const float2*)&Ws[k + 1][f0];
        float2 w2 = *(const float2*)&Ws[k + 2][f0];
        float2 w3 = *(const float2*)&Ws[k + 3][f0];
#pragma unroll
        for (int i = 0; i < 16; i++) {
            float4 a = *(const float4*)(a0p + (size_t)i * 80 + k);
            acc[i].x += a.x * w0.x + a.y * w1.x + a.z * w2.x + a.w * w3.x;
            acc[i].y += a.x * w0.y + a.y * w1.y + a.z * w2.y + a.w * w3.y;
        }
    }
    float2 bv = *(const float2*)&bias[f0];
#pragma unroll
    for (int i = 0; i < 16; i++) {
        float2 o;
        o.x = fmaxf(acc[i].x + bv.x, 0.f);
        o.y = fmaxf(acc[i].y + bv.y, 0.f);
        *(float2*)&out[(size_t)(n0 + i) * 128 + f0] = o;
    }
}

// ---------------- gemm2+pool: relu(agg2[N,128] @ W2[128,256] + b2) -> segmax ----------------
// 4 waves/block; wave owns 8 nodes; lane covers 4 feats. W2 in 16-k LDS chunks;
// A via wave-uniform loads. Pool: flush-on-change (batch sorted).
__global__ __launch_bounds__(256) void k_gemm2_pool(const float* __restrict__ A,
    const float* __restrict__ W, const float* __restrict__ bias,
    const int* __restrict__ batch, unsigned* __restrict__ gmax) {
    __shared__ float Ws[16][256];   // 16 KB
    int tid = threadIdx.x;
    int wv = tid >> 6, l = tid & 63;
    int task = __builtin_amdgcn_readfirstlane(blockIdx.x * 4 + wv);  // 12500 tasks
    int n0 = task * 8;
    const float* a0p = A + (size_t)n0 * 128;
    int f0 = l * 4;
    float4 acc[8];
#pragma unroll
    for (int i = 0; i < 8; i++) acc[i] = make_float4(0.f, 0.f, 0.f, 0.f);

    for (int c = 0; c < 8; c++) {
        int k0 = c * 16;
        __syncthreads();
        for (int i = tid; i < 1024; i += 256) {   // 16x256 floats as float4
            int k = i >> 6, f4 = (i & 63) << 2;
            *(float4*)&Ws[k][f4] = *(const float4*)&W[(size_t)(k0 + k) * 256 + f4];
        }
        __syncthreads();
#pragma unroll
        for (int kk = 0; kk < 16; kk += 4) {
            float4 w0 = *(const float4*)&Ws[kk + 0][f0];
            float4 w1 = *(const float4*)&Ws[kk + 1][f0];
            float4 w2 = *(const float4*)&Ws[kk + 2][f0];
            float4 w3 = *(const float4*)&Ws[kk + 3][f0];
#pragma unroll
            for (int i = 0; i < 8; i++) {
                float4 a = *(const float4*)(a0p + (size_t)i * 128 + k0 + kk);
                acc[i].x += a.x * w0.x + a.y * w1.x + a.z * w2.x + a.w * w3.x;
                acc[i].y += a.x * w0.y + a.y * w1.y + a.z * w2.y + a.w * w3.y;
                acc[i].z += a.x * w0.z + a.y * w1.z + a.z * w2.z + a.w * w3.z;
                acc[i].w += a.x * w0.w + a.y * w1.w + a.z * w2.w + a.w * w3.w;
            }
        }
    }

    float4 bv = *(const float4*)&bias[f0];
    int curg = -1;
    float4 m = make_float4(0.f, 0.f, 0.f, 0.f);
#pragma unroll
    for (int i = 0; i < 8; i++) {
        int g = batch[n0 + i];
        float4 v;
        v.x = fmaxf(acc[i].x + bv.x, 0.f); v.y = fmaxf(acc[i].y + bv.y, 0.f);
        v.z = fmaxf(acc[i].z + bv.z, 0.f); v.w = fmaxf(acc[i].w + bv.w, 0.f);
        if (g != curg) {
            if (curg >= 0) {
                unsigned* gp = &gmax[(size_t)curg * 256 + f0];
                atomicMax(&gp[0], __float_as_uint(m.x));
                atomicMax(&gp[1], __float_as_uint(m.y));
                atomicMax(&gp[2], __float_as_uint(m.z));
                atomicMax(&gp[3], __float_as_uint(m.w));
            }
            curg = g; m = v;
        } else {
            m.x = fmaxf(m.x, v.x); m.y = fmaxf(m.y, v.y);
            m.z = fmaxf(m.z, v.z); m.w = fmaxf(m.w, v.w);
        }
    }
    if (curg >= 0) {
        unsigned* gp = &gmax[(size_t)curg * 256 + f0];
        atomicMax(&gp[0], __float_as_uint(m.x));
        atomicMax(&gp[1], __float_as_uint(m.y));
        atomicMax(&gp[2], __float_as_uint(m.z));
        atomicMax(&gp[3], __float_as_uint(m.w));
    }
}

// ---------------- MLP head ----------------

__global__ __launch_bounds__(256) void k_gemm3(const float* __restrict__ A,
    const float* __restrict__ W, const float* __restrict__ bias,
    float* __restrict__ out) {
    __shared__ float rs[256];
    int g = blockIdx.x, tid = threadIdx.x;
    rs[tid] = A[g * 256 + tid];
    __syncthreads();
    float acc[4] = {0.f, 0.f, 0.f, 0.f};
    for (int k = 0; k < 256; k++) {
        float a = rs[k];
#pragma unroll
        for (int j = 0; j < 4; j++) acc[j] += a * W[k * 1024 + tid + j * 256];
    }
#pragma unroll
    for (int j = 0; j < 4; j++) {
        int f = tid + j * 256;
        out[g * 1024 + f] = fmaxf(acc[j] + bias[f], 0.0f);
    }
}

__global__ __launch_bounds__(128) void k_gemm4(const float* __restrict__ A,
    const float* __restrict__ W, const float* __restrict__ bias,
    float* __restrict__ out) {
    __shared__ float rs[1024];
    int g = blockIdx.x, tid = threadIdx.x;
    for (int i = tid; i < 1024; i += 128) rs[i] = A[g * 1024 + i];
    __syncthreads();
    float acc = 0.0f;
    for (int k = 0; k < 1024; k++) acc += rs[k] * W[k * 128 + tid];
    out[g * 128 + tid] = acc + bias[tid];
}

extern "C" void kernel_launch(void* const* d_in, const int* in_sizes, int n_in,
                              void* d_out, int out_size, void* d_ws, size_t ws_size,
                              hipStream_t stream) {
    const float* x    = (const float*)d_in[0];
    const int*   ei   = (const int*)d_in[1];
    const int*   batch= (const int*)d_in[2];
    const float* W1   = (const float*)d_in[3];
    const float* b1   = (const float*)d_in[4];
    const float* W2   = (const float*)d_in[5];
    const float* b2   = (const float*)d_in[6];
    const float* Wg1  = (const float*)d_in[7];
    const float* bg1  = (const float*)d_in[8];
    const float* Wg2  = (const float*)d_in[9];
    const float* bg2  = (const float*)d_in[10];
    const int* src = ei;
    const int* dst = ei + NE;

    char* w8 = (char*)d_ws;
    int*   cnt     = (int*)w8;                 w8 += (size_t)NN * 4;
    int*   row_ptr = (int*)w8;                 w8 += (size_t)(NN + 4) * 4;
    int*   cursor  = (int*)w8;                 w8 += (size_t)NN * 4;
    int*   bsum    = (int*)w8;                 w8 += 128 * 4;
    int2*  es      = (int2*)w8;                w8 += (size_t)NE * 8;
    float* dinv    = (float*)w8;               w8 += (size_t)NN * 4;
    float* agg1    = (float*)w8;               w8 += (size_t)NN * 80 * 4;   // stride 80
    float* h1      = (float*)w8;               w8 += (size_t)NN * 128 * 4;
    float* agg2    = (float*)w8;               w8 += (size_t)NN * 128 * 4;
    unsigned* gmax = (unsigned*)w8;            w8 += (size_t)NG * 256 * 4;
    float* g1      = (float*)w8;               w8 += (size_t)NG * 1024 * 4;

    // CSR build
    k_zero_int<<<(NN + 255) / 256, 256, 0, stream>>>(cnt, NN);
    k_hist<<<(NE + 255) / 256, 256, 0, stream>>>(dst, cnt, NE);
    k_prep<<<(NG * 256 + 255) / 256, 256, 0, stream>>>(cnt, dinv, (float*)gmax);
    k_bsum<<<NBLK, 256, 0, stream>>>(cnt, bsum);
    k_scan_bsum<<<1, 128, 0, stream>>>(bsum, row_ptr);
    k_scan_blocks<<<NBLK, 256, 0, stream>>>(cnt, bsum, row_ptr, cursor);
    k_fillslots<<<(NE + 255) / 256, 256, 0, stream>>>(src, dst, dinv, cursor, es, NE);

    // layer 1
    k_gather78<<<NN / 4, 256, 0, stream>>>(x, row_ptr, es, dinv, agg1);
    k_gemm1<<<(NN / 16 + 3) / 4, 256, 0, stream>>>(agg1, W1, b1, h1);

    // layer 2
    k_gather128<<<NN / 4, 256, 0, stream>>>(h1, row_ptr, es, dinv, agg2);
    k_gemm2_pool<<<NN / 32, 256, 0, stream>>>(agg2, W2, b2, batch, gmax);

    // MLP head
    k_gemm3<<<NG, 256, 0, stream>>>((const float*)gmax, Wg1, bg1, g1);
    k_gemm4<<<NG, 128, 0, stream>>>(g1, Wg2, bg2, (float*)d_out);
}